// Round 7
// baseline (363.491 us; speedup 1.0000x reference)
//
#include <hip/hip_runtime.h>

#define C_IN 256
#define C_OUT 256
#define NH 4
#define HD 64
#define NEG_SLOPE 0.2f

typedef _Float16 half8 __attribute__((ext_vector_type(8)));
typedef _Float16 half4v __attribute__((ext_vector_type(4)));
typedef float floatx4 __attribute__((ext_vector_type(4)));

// ---------------------------------------------------------------------------
// K1: collapse (Wl,att_l)->Ws[:,0:4], (Wr,att_r)->Ws[:,4:8]; biases -> bs[8].
// ---------------------------------------------------------------------------
__global__ void make_eff_w(const float* __restrict__ Wl, const float* __restrict__ Wr,
                           const float* __restrict__ bl, const float* __restrict__ br,
                           const float* __restrict__ attl, const float* __restrict__ attr,
                           float* __restrict__ Ws, float* __restrict__ bs)
{
    int c = blockIdx.x;
    int t = threadIdx.x;          // t = h*64 + d
    int h = t >> 6, d = t & 63;
    float al = attl[t], ar = attr[t];
    float vl, vr;
    if (c < C_IN) { vl = Wl[c * C_OUT + t] * al; vr = Wr[c * C_OUT + t] * ar; }
    else          { vl = bl[t] * al;             vr = br[t] * ar; }
#pragma unroll
    for (int off = 32; off >= 1; off >>= 1) {
        vl += __shfl_xor(vl, off, 64);
        vr += __shfl_xor(vr, off, 64);
    }
    if (d == 0) {
        if (c < C_IN) { Ws[c * 8 + h] = vl; Ws[c * 8 + 4 + h] = vr; }
        else          { bs[h] = vl;         bs[4 + h] = vr; }
    }
}

// ---------------------------------------------------------------------------
// Transpose Wv (k-major fp32) -> WvT (n-major f16).
// ---------------------------------------------------------------------------
__global__ void transpose_w(const float* __restrict__ Wv, _Float16* __restrict__ WvT)
{
    int idx = blockIdx.x * 256 + threadIdx.x;
    int n = idx >> 8, k = idx & 255;
    WvT[n * 256 + k] = (_Float16)Wv[k * 256 + n];
}

// ---------------------------------------------------------------------------
// GEMM v7: barrier-free, LDS-free streaming GEMM for tall-skinny M x 256.
// One wave owns a 16-row x 256-col output strip. MFMA fragments are fed
// DIRECTLY from global:
//   A-frag: lane reads x[(m0 + r16)*256 + k0 + quad*8 .. +8] (8 f32 -> f16)
//   B-frag: lane reads WvT[(cg*16 + r16)*256 + k0 + quad*8] (16B, L1/L2-hit)
// (identical index patterns to the old As/Bs reads, minus the LDS round-trip,
//  the two barriers per K-step, and the f32->LDS->f16 staging).
// B (131 KB) is cache-resident; x has zero reuse -> staging bought nothing.
// node_scores stays fused: sacc[8] += x*Ws per lane (Ws rows are broadcast
// L1 loads), quad-tree shfl reduce, pure-f32 FMA (absmax gate unchanged).
// ---------------------------------------------------------------------------
__global__ __launch_bounds__(256) void gemm_xv(const float* __restrict__ x,
    const _Float16* __restrict__ WvT, const float* __restrict__ bv,
    const float* __restrict__ Ws, const float* __restrict__ bs,
    _Float16* __restrict__ xv, float* __restrict__ s, int M)
{
    int wv   = blockIdx.x * 4 + (threadIdx.x >> 6);
    int lane = threadIdx.x & 63;
    int r16 = lane & 15, quad = lane >> 4;
    int m0 = wv * 16;
    if (m0 >= M) return;

    int arow = m0 + r16;
    int arow_c = arow < M ? arow : M - 1;          // load-clamp (stores guarded)
    const float* xrow = x + (size_t)arow_c * 256 + quad * 8;

    floatx4 acc[16];
#pragma unroll
    for (int cg = 0; cg < 16; ++cg) acc[cg] = (floatx4){0.f, 0.f, 0.f, 0.f};
    float sacc[8];
#pragma unroll
    for (int j = 0; j < 8; ++j) sacc[j] = 0.f;

    for (int k0 = 0; k0 < 256; k0 += 32) {
        float4 xa = *(const float4*)(xrow + k0);
        float4 xb = *(const float4*)(xrow + k0 + 4);
        half8 af;
        af[0] = (_Float16)xa.x; af[1] = (_Float16)xa.y;
        af[2] = (_Float16)xa.z; af[3] = (_Float16)xa.w;
        af[4] = (_Float16)xb.x; af[5] = (_Float16)xb.y;
        af[6] = (_Float16)xb.z; af[7] = (_Float16)xb.w;

        // s partial: this lane's 8 k-values hit Ws rows k0+quad*8+j2 (broadcast).
        const float* wsr = Ws + (unsigned)(k0 + quad * 8) * 8;
        float xf[8] = {xa.x, xa.y, xa.z, xa.w, xb.x, xb.y, xb.z, xb.w};
#pragma unroll
        for (int j2 = 0; j2 < 8; ++j2) {
            float4 wa = *(const float4*)(wsr + j2 * 8);
            float4 wb = *(const float4*)(wsr + j2 * 8 + 4);
            sacc[0] += xf[j2] * wa.x; sacc[1] += xf[j2] * wa.y;
            sacc[2] += xf[j2] * wa.z; sacc[3] += xf[j2] * wa.w;
            sacc[4] += xf[j2] * wb.x; sacc[5] += xf[j2] * wb.y;
            sacc[6] += xf[j2] * wb.z; sacc[7] += xf[j2] * wb.w;
        }

#pragma unroll
        for (int cg = 0; cg < 16; ++cg) {
            half8 bf = *(const half8*)(WvT + (unsigned)((cg * 16 + r16) * 256 + k0 + quad * 8));
            acc[cg] = __builtin_amdgcn_mfma_f32_16x16x32_f16(af, bf, acc[cg], 0, 0, 0);
        }
    }

    // ---- xv epilogue: C layout col=lane&15, row=quad*4+rr. ----
#pragma unroll
    for (int cg = 0; cg < 16; ++cg) {
        int gcol = cg * 16 + r16;
        float bias = bv[gcol];
#pragma unroll
        for (int rr = 0; rr < 4; ++rr) {
            int grow = m0 + quad * 4 + rr;
            if (grow < M)
                xv[(size_t)grow * 256 + gcol] = (_Float16)(acc[cg][rr] + bias);
        }
    }

    // ---- s epilogue: reduce over the 4 quads (lane bits 4-5). ----
#pragma unroll
    for (int o = 16; o <= 32; o <<= 1)
#pragma unroll
        for (int j = 0; j < 8; ++j) sacc[j] += __shfl_xor(sacc[j], o, 64);
    if (quad == 0 && arow < M) {
        *(float4*)(s + (size_t)arow * 8)     = make_float4(sacc[0] + bs[0], sacc[1] + bs[1], sacc[2] + bs[2], sacc[3] + bs[3]);
        *(float4*)(s + (size_t)arow * 8 + 4) = make_float4(sacc[4] + bs[4], sacc[5] + bs[5], sacc[6] + bs[6], sacc[7] + bs[7]);
    }
}

// ---------------------------------------------------------------------------
// CSR build (v6: 4 edges/thread via int4 loads).
// ---------------------------------------------------------------------------
__global__ void deg_kernel(const int* __restrict__ dst, int* __restrict__ deg, int E)
{
    int i = blockIdx.x * 256 + threadIdx.x;
    int base = i * 4;
    if (base >= E) return;
    if (base + 4 <= E) {
        int4 d = *(const int4*)(dst + base);
        atomicAdd(&deg[d.x], 1);
        atomicAdd(&deg[d.y], 1);
        atomicAdd(&deg[d.z], 1);
        atomicAdd(&deg[d.w], 1);
    } else {
        for (int k = base; k < E; ++k) atomicAdd(&deg[dst[k]], 1);
    }
}

__global__ void scan_part(const int* __restrict__ deg, int* __restrict__ partials,
                          int N, int chunk)
{
    __shared__ int sd[256];
    int b = blockIdx.x, t = threadIdx.x;
    int idx = b * chunk + t;
    int v = (t < chunk && idx < N) ? deg[idx] : 0;
    sd[t] = v; __syncthreads();
    for (int off = 128; off >= 1; off >>= 1) {
        if (t < off) sd[t] += sd[t + off];
        __syncthreads();
    }
    if (t == 0) partials[b] = sd[0];
}

__global__ void scan_partials(const int* __restrict__ partials, int* __restrict__ pscan)
{
    __shared__ int sd[256];
    int t = threadIdx.x;
    int v = partials[t];
    sd[t] = v; __syncthreads();
    for (int off = 1; off < 256; off <<= 1) {
        int x = (t >= off) ? sd[t - off] : 0;
        __syncthreads();
        sd[t] += x;
        __syncthreads();
    }
    pscan[t] = sd[t] - v;  // exclusive
}

__global__ void scan_final(const int* __restrict__ deg, const int* __restrict__ pscan,
                           int* __restrict__ offs, int N, int chunk)
{
    __shared__ int sd[256];
    int b = blockIdx.x, t = threadIdx.x;
    int idx = b * chunk + t;
    int v = (t < chunk && idx < N) ? deg[idx] : 0;
    sd[t] = v; __syncthreads();
    for (int off = 1; off < 256; off <<= 1) {
        int x = (t >= off) ? sd[t - off] : 0;
        __syncthreads();
        sd[t] += x;
        __syncthreads();
    }
    int incl = sd[t], excl = incl - v;
    int base = pscan[b];
    if (t < chunk && idx < N) offs[idx] = base + excl;
    if (idx == N - 1) offs[N] = base + incl;  // == E
}

__global__ void scatter_kernel(const int* __restrict__ src, const int* __restrict__ dst,
                               const int* __restrict__ offs, int* __restrict__ cursor,
                               int* __restrict__ csr_src, int E)
{
    int i = blockIdx.x * 256 + threadIdx.x;
    int base = i * 4;
    if (base >= E) return;
    if (base + 4 <= E) {
        int4 d  = *(const int4*)(dst + base);
        int4 sv = *(const int4*)(src + base);
        int p0 = offs[d.x] + atomicAdd(&cursor[d.x], 1); csr_src[p0] = sv.x;
        int p1 = offs[d.y] + atomicAdd(&cursor[d.y], 1); csr_src[p1] = sv.y;
        int p2 = offs[d.z] + atomicAdd(&cursor[d.z], 1); csr_src[p2] = sv.z;
        int p3 = offs[d.w] + atomicAdd(&cursor[d.w], 1); csr_src[p3] = sv.w;
    } else {
        for (int k = base; k < E; ++k) {
            int d = dst[k];
            int p = offs[d] + atomicAdd(&cursor[d], 1);
            csr_src[p] = src[k];
        }
    }
}

// ---------------------------------------------------------------------------
// agg = (hlr + segsum(hlr[src] by dst)) / (1+deg). EIGHT threads per node.
// ---------------------------------------------------------------------------
__global__ void agg_kernel(const float* __restrict__ s, const int* __restrict__ csr_src,
                           const int* __restrict__ offs, const int* __restrict__ deg,
                           float* __restrict__ aggl, float* __restrict__ aggr, int N)
{
    int gid = blockIdx.x * 256 + threadIdx.x;
    int n = gid >> 3, c = gid & 7;
    if (n >= N) return;
    int off = offs[n], dg = deg[n];
    float acc = s[(size_t)n * 8 + c];
    int i = 0;
    for (; i + 4 <= dg; i += 4) {
        int p0 = csr_src[off + i];
        int p1 = csr_src[off + i + 1];
        int p2 = csr_src[off + i + 2];
        int p3 = csr_src[off + i + 3];
        float v0 = s[(size_t)p0 * 8 + c];
        float v1 = s[(size_t)p1 * 8 + c];
        float v2 = s[(size_t)p2 * 8 + c];
        float v3 = s[(size_t)p3 * 8 + c];
        acc += (v0 + v1) + (v2 + v3);
    }
    for (; i < dg; ++i) acc += s[(size_t)csr_src[off + i] * 8 + c];
    acc *= 1.0f / (1.0f + (float)dg);
    if (c < 4) aggl[(size_t)n * 4 + c]     = acc;
    else       aggr[(size_t)n * 4 + c - 4] = acc;
}

// ---------------------------------------------------------------------------
// Fused softmax + value aggregation — v5 (unchanged).
// ---------------------------------------------------------------------------
template<int SZ>
__device__ __forceinline__ void gather_sub(int cs, float w, int base, int grp, int lof,
    const _Float16* __restrict__ xv,
    float& o0, float& o1, float& o2, float& o3)
{
    half4v hv[SZ];
#pragma unroll
    for (int j = 0; j < SZ; ++j) {
        int sidx = __builtin_amdgcn_readlane(cs, base + j);   // SGPR row index
        hv[j] = *(const half4v*)(xv + (((unsigned)sidx << 8) + lof));
    }
#pragma unroll
    for (int j = 0; j < SZ; ++j) {
        float wv = __shfl(w, grp + base + j, 64);
        o0 += wv * (float)hv[j][0];
        o1 += wv * (float)hv[j][1];
        o2 += wv * (float)hv[j][2];
        o3 += wv * (float)hv[j][3];
    }
}

__device__ __forceinline__ void do_chunk(int cs, float w, int cnt, int grp, int lof,
    const _Float16* __restrict__ xv,
    float& o0, float& o1, float& o2, float& o3)
{
    if (cnt == 16) { gather_sub<16>(cs, w, 0, grp, lof, xv, o0, o1, o2, o3); return; }
    int b = 0;
    if (cnt & 8) { gather_sub<8>(cs, w, b, grp, lof, xv, o0, o1, o2, o3); b += 8; }
    if (cnt & 4) { gather_sub<4>(cs, w, b, grp, lof, xv, o0, o1, o2, o3); b += 4; }
    if (cnt & 2) { gather_sub<2>(cs, w, b, grp, lof, xv, o0, o1, o2, o3); b += 2; }
    if (cnt & 1) { gather_sub<1>(cs, w, b, grp, lof, xv, o0, o1, o2, o3); }
}

__global__ __launch_bounds__(256) void attn_out(const float* __restrict__ aggl,
    const float* __restrict__ aggr, const int* __restrict__ csr_src,
    const int* __restrict__ offs, const int* __restrict__ deg,
    const _Float16* __restrict__ xv, float* __restrict__ out, int N)
{
    int wid = threadIdx.x >> 6, lane = threadIdx.x & 63;
    int n = blockIdx.x * 4 + wid;
    if (n >= N) return;
    int myhead = lane >> 4, myedge = lane & 15, grp = lane & 48;
    int lof = lane << 2;
    int off = offs[n], dg = deg[n];
    const int* cb = csr_src + off;
    float ar = aggr[(unsigned)(n * 4 + myhead)];

    float o0 = 0.f, o1 = 0.f, o2 = 0.f, o3 = 0.f;

    // ---- Phase A: all weight-phase loads issued upfront (independent). ----
    int cs0 = 0, cs1 = 0, cs2 = 0, cs3 = 0;
    int e1 = myedge + 16, e2 = myedge + 32, e3 = myedge + 48;
    if (myedge < dg) cs0 = cb[myedge];
    if (e1 < dg)     cs1 = cb[e1];
    if (e2 < dg)     cs2 = cb[e2];
    if (e3 < dg)     cs3 = cb[e3];
    float a0 = 0.f, a1 = 0.f, a2 = 0.f, a3 = 0.f;
    if (myedge < dg) a0 = aggl[(unsigned)((cs0 << 2) + myhead)];
    if (e1 < dg)     a1 = aggl[(unsigned)((cs1 << 2) + myhead)];
    if (e2 < dg)     a2 = aggl[(unsigned)((cs2 << 2) + myhead)];
    if (e3 < dg)     a3 = aggl[(unsigned)((cs3 << 2) + myhead)];
    float w0 = 0.f, w1 = 0.f, w2 = 0.f, w3 = 0.f;
    if (myedge < dg) { float e = a0 + ar; e = (e > 0.f) ? e : NEG_SLOPE * e; w0 = __expf(e); }
    if (e1 < dg)     { float e = a1 + ar; e = (e > 0.f) ? e : NEG_SLOPE * e; w1 = __expf(e); }
    if (e2 < dg)     { float e = a2 + ar; e = (e > 0.f) ? e : NEG_SLOPE * e; w2 = __expf(e); }
    if (e3 < dg)     { float e = a3 + ar; e = (e > 0.f) ? e : NEG_SLOPE * e; w3 = __expf(e); }
    float denom = w0; denom += w1; denom += w2; denom += w3;

    // ---- Phase B: gather rounds, weights already in registers. ----
    int c0 = dg < 16 ? dg : 16;
    do_chunk(cs0, w0, c0, grp, lof, xv, o0, o1, o2, o3);
    if (dg > 16) {
        int c1 = dg - 16 < 16 ? dg - 16 : 16;
        do_chunk(cs1, w1, c1, grp, lof, xv, o0, o1, o2, o3);
    }
    if (dg > 32) {
        int c2 = dg - 32 < 16 ? dg - 32 : 16;
        do_chunk(cs2, w2, c2, grp, lof, xv, o0, o1, o2, o3);
    }
    if (dg > 48) {
        int c3 = dg - 48 < 16 ? dg - 48 : 16;
        do_chunk(cs3, w3, c3, grp, lof, xv, o0, o1, o2, o3);
    }
    // Fallback for dg > 64 (essentially never for Poisson(16); correctness).
    for (int b = 64; b < dg; b += 16) {
        int cs = 0; float w = 0.f;
        if (b + myedge < dg) {
            cs = cb[b + myedge];
            float e = aggl[(unsigned)((cs << 2) + myhead)] + ar;
            e = (e > 0.f) ? e : NEG_SLOPE * e;
            w = __expf(e);
        }
        denom += w;
        int cnt = dg - b < 16 ? dg - b : 16;
        do_chunk(cs, w, cnt, grp, lof, xv, o0, o1, o2, o3);
    }

    // Sum denom over the 16 lanes of this head group.
#pragma unroll
    for (int o = 1; o <= 8; o <<= 1) denom += __shfl_xor(denom, o, 64);
    float inv = 1.0f / fmaxf(denom, 1e-16f);
    floatx4 res = {o0 * inv, o1 * inv, o2 * inv, o3 * inv};
    __builtin_nontemporal_store(res, (floatx4*)(out + (size_t)n * 256 + lof));
}

// ---------------------------------------------------------------------------
extern "C" void kernel_launch(void* const* d_in, const int* in_sizes, int n_in,
                              void* d_out, int out_size, void* d_ws, size_t ws_size,
                              hipStream_t stream)
{
    const float* x    = (const float*)d_in[0];
    const int*   src  = (const int*)d_in[1];
    const int*   dst  = (const int*)d_in[2];
    const float* Wl   = (const float*)d_in[3];
    const float* bl   = (const float*)d_in[4];
    const float* Wr   = (const float*)d_in[5];
    const float* br   = (const float*)d_in[6];
    const float* Wv   = (const float*)d_in[7];
    const float* bv   = (const float*)d_in[8];
    const float* attl = (const float*)d_in[9];
    const float* attr = (const float*)d_in[10];
    float* out = (float*)d_out;

    int N = in_sizes[0] / C_IN;
    int E = in_sizes[1];

    char* p = (char*)d_ws;
    auto alloc = [&](size_t bytes) -> void* {
        uintptr_t q = (uintptr_t)p;
        q = (q + 255) & ~(uintptr_t)255;
        p = (char*)(q + bytes);
        return (void*)q;
    };
    float* Ws     = (float*)alloc((size_t)C_IN * 8 * sizeof(float));
    float* bs     = (float*)alloc(8 * sizeof(float));
    float* s      = (float*)alloc((size_t)N * 8 * sizeof(float));
    float* aggl   = (float*)alloc((size_t)N * 4 * sizeof(float));
    float* aggr   = (float*)alloc((size_t)N * 4 * sizeof(float));
    int* deg      = (int*)alloc((size_t)N * sizeof(int));
    int* offs     = (int*)alloc((size_t)(N + 1) * sizeof(int));
    int* cursor   = (int*)alloc((size_t)N * sizeof(int));
    int* partials = (int*)alloc(256 * sizeof(int));
    int* pscan    = (int*)alloc(256 * sizeof(int));
    int* csr_src  = (int*)alloc((size_t)E * sizeof(int));
    _Float16* WvT = (_Float16*)alloc((size_t)C_IN * C_OUT * sizeof(_Float16));
    _Float16* xv  = (_Float16*)alloc((size_t)N * C_OUT * sizeof(_Float16));

    hipMemsetAsync(deg, 0, (size_t)N * sizeof(int), stream);
    hipMemsetAsync(cursor, 0, (size_t)N * sizeof(int), stream);

    make_eff_w<<<C_IN + 1, 256, 0, stream>>>(Wl, Wr, bl, br, attl, attr, Ws, bs);
    transpose_w<<<(C_IN * C_OUT) / 256, 256, 0, stream>>>(Wv, WvT);
    int nstrips = (N + 15) / 16;
    gemm_xv<<<(nstrips + 3) / 4, 256, 0, stream>>>(x, WvT, bv, Ws, bs, xv, s, N);
    deg_kernel<<<((E + 3) / 4 + 255) / 256, 256, 0, stream>>>(dst, deg, E);
    int chunk = (N + 255) / 256;
    scan_part<<<256, 256, 0, stream>>>(deg, partials, N, chunk);
    scan_partials<<<1, 256, 0, stream>>>(partials, pscan);
    scan_final<<<256, 256, 0, stream>>>(deg, pscan, offs, N, chunk);
    scatter_kernel<<<((E + 3) / 4 + 255) / 256, 256, 0, stream>>>(src, dst, offs, cursor, csr_src, E);
    agg_kernel<<<(N * 8 + 255) / 256, 256, 0, stream>>>(s, csr_src, offs, deg, aggl, aggr, N);
    attn_out<<<(N + 3) / 4, 256, 0, stream>>>(aggl, aggr, csr_src, offs, deg, xv, out, N);
}